// Round 13
// baseline (350.517 us; speedup 1.0000x reference)
//
#include <hip/hip_runtime.h>
#include <hip/hip_bf16.h>

typedef unsigned short u16;
typedef __attribute__((ext_vector_type(8))) short bf16x8;
typedef __attribute__((ext_vector_type(4))) float f32x4;

#define LOG2E_F 1.4426950408889634f
#define QSCALE (0.08838834764831845f * 7.625595228825695f * 1.4426950408889634f)

__device__ __forceinline__ u16 f2bf(float f) {
  unsigned x = __float_as_uint(f);
  unsigned r = (x + 0x7fffu + ((x >> 16) & 1u)) >> 16;  // RNE
  return (u16)r;
}
__device__ __forceinline__ float bf2f(u16 u) {
  return __uint_as_float(((unsigned)u) << 16);
}
__device__ __forceinline__ float exp2a(float x) {
  float r;
  asm("v_exp_f32 %0, %1" : "=v"(r) : "v"(x));
  return r;
}
__device__ __forceinline__ unsigned cvtpk(float lo, float hi) {
  unsigned r;
  asm("v_cvt_pk_bf16_f32 %0, %1, %2" : "=v"(r) : "v"(lo), "v"(hi));
  return r;
}

__device__ __forceinline__ void gload_lds16(const void* g, void* l) {
  __builtin_amdgcn_global_load_lds(
      (__attribute__((address_space(1))) void*)(g),
      (__attribute__((address_space(3))) void*)(l), 16, 0, 0);
}

__device__ __forceinline__ f32x4 mfma16(bf16x8 a, bf16x8 b, f32x4 c) {
  return __builtin_amdgcn_mfma_f32_16x16x32_bf16(a, b, c, 0, 0, 0);
}

// ---- fused setup: weight transpose+convert, x convert, maskflag, trig ----
__global__ __launch_bounds__(256) void setup(const float* __restrict__ Wq,
                                             const float* __restrict__ Wk,
                                             const float* __restrict__ Wv,
                                             const float* __restrict__ Wo,
                                             u16* __restrict__ wqkvt,
                                             u16* __restrict__ wot,
                                             const float4* __restrict__ x,
                                             ushort4* __restrict__ xb,
                                             const float4* __restrict__ mask,
                                             int* __restrict__ flag,
                                             const int* __restrict__ row_ids,
                                             const int* __restrict__ col_ids,
                                             float4* __restrict__ trig) {
  int bid = blockIdx.x;
  int tid = threadIdx.x;
  if (bid >= 10240) {
    bid -= 10240;
    if (bid < 8192) {  // cvt_x: 2048x4096 f32 -> bf16
      size_t i = (size_t)bid * 256 + tid;
      float4 v = x[i];
      ushort4 o;
      o.x = f2bf(v.x); o.y = f2bf(v.y); o.z = f2bf(v.z); o.w = f2bf(v.w);
      xb[i] = o;
    } else if (bid < 12288) {  // maskflag: 2048x2048
      size_t i = (size_t)(bid - 8192) * 256 + tid;
      float4 v = mask[i];
      if (v.x != 0.f || v.y != 0.f || v.z != 0.f || v.w != 0.f) atomicOr(flag, 1);
    } else {  // trig: 2048 tokens x 32 freqs
      int idx = (bid - 12288) * 256 + tid;
      int tok = idx >> 5, i = idx & 31;
      float inv = exp2f(-(float)i * 0.41524101186092030f);
      float ar = (float)row_ids[tok] * inv;
      float ac = (float)col_ids[tok] * inv * 1.618033988749895f;
      float4 o;
      o.x = cosf(ar); o.y = sinf(ar); o.z = cosf(ac); o.w = sinf(ac);
      trig[idx] = o;
    }
    return;
  }
  // weight transpose+convert: W [4096][N] f32 -> Wt [N][4096] bf16
  __shared__ float t[64][65];
  const float* src;
  u16* dst;
  int N;
  if (bid < 4096)      { src = Wq; dst = wqkvt;                       N = 4096; }
  else if (bid < 5120) { src = Wk; dst = wqkvt + (size_t)4096 * 4096; N = 1024; bid -= 4096; }
  else if (bid < 6144) { src = Wv; dst = wqkvt + (size_t)5120 * 4096; N = 1024; bid -= 5120; }
  else                 { src = Wo; dst = wot;                         N = 4096; bid -= 6144; }
  int kt = bid & 63, nt = bid >> 6;
  int k0 = kt * 64, n0 = nt * 64;
#pragma unroll
  for (int it = 0; it < 16; ++it) {
    int idx = it * 256 + tid;
    int row = idx >> 6, col = idx & 63;
    t[row][col] = src[(size_t)(k0 + row) * N + n0 + col];
  }
  __syncthreads();
#pragma unroll
  for (int it = 0; it < 8; ++it) {
    int idx = it * 256 + tid;
    int nrow = idx >> 5, kc = idx & 31;
    ushort2 o;
    o.x = f2bf(t[kc * 2][nrow]);
    o.y = f2bf(t[kc * 2 + 1][nrow]);
    *(ushort2*)&dst[(size_t)(n0 + nrow) * 4096 + k0 + kc * 2] = o;
  }
}

// ---------------- RMSNorm + gg-RoPE (in-place on QK buffer) ----------------
__global__ __launch_bounds__(256) void rope_kernel(u16* __restrict__ qk,
                                                   const float4* __restrict__ trig,
                                                   const float* __restrict__ qw,
                                                   const float* __restrict__ kw) {
  const int tok = blockIdx.x;
  const int tid = threadIdx.x;
  const int w = tid >> 6, lane = tid & 63;
  float4 t4 = trig[tok * 32 + (lane & 31)];
  float sgn = (lane < 32) ? -1.0f : 1.0f;

  for (int it = 0; it < 10; ++it) {
    int hh = w + it * 4;
    bool isQ = (hh < 32);
    int colbase = isQ ? hh * 128 : 4096 + (hh - 32) * 128;
    const float* nw = isQ ? qw : kw;
    float scale = isQ ? QSCALE : 1.0f;
    u16* p = qk + (size_t)tok * 5120 + colbase;
    float v1 = bf2f(p[lane]);
    float v2 = bf2f(p[64 + lane]);
    float w1 = nw[lane], w2 = nw[64 + lane];
    float ss = v1 * v1 + v2 * v2;
    ss += __shfl_xor(ss, 1);  ss += __shfl_xor(ss, 2);  ss += __shfl_xor(ss, 4);
    ss += __shfl_xor(ss, 8);  ss += __shfl_xor(ss, 16); ss += __shfl_xor(ss, 32);
    float rinv = rsqrtf(ss * (1.0f / 128.0f) + 1e-6f);
    float n1 = v1 * rinv * w1;
    float n2 = v2 * rinv * w2;
    float p1 = __shfl_xor(n1, 32);
    float p2 = __shfl_xor(n2, 32);
    float r1 = n1 * t4.x + sgn * p1 * t4.y;
    float r2 = n2 * t4.z + sgn * p2 * t4.w;
    p[lane]      = f2bf(r1 * scale);
    p[64 + lane] = f2bf(r2 * scale);
  }
}

// ======== 8-phase GEMM: C[M][N] = A[M][4096] * Bt[N][4096]^T ========
// MODE 0: BM=256, BN=192, grid 8x32=256 (1/CU, LDS 112KB). Out: qk / Vt.
// MODE 1: BM=128, BN=128, grid 16x32=512 (2/CU, LDS 64KB). Out: f32 d_out.
template <int MODE>
__global__ __launch_bounds__(512, (MODE == 0) ? 2 : 4)
void gemm256(const u16* __restrict__ A, const u16* __restrict__ Bt,
             void* __restrict__ C0, u16* __restrict__ Vt, int nnt) {
  extern __shared__ char smem[];
  const int tid = threadIdx.x, lane = tid & 63, w = tid >> 6;
  const int l15 = lane & 15, l4 = lane >> 4;
  const int wr = w >> 2, wc = w & 3;
  constexpr int NF = (MODE == 0) ? 3 : 2;
  constexpr int BNW = (MODE == 0) ? 48 : 32;
  constexpr int AHALF = (MODE == 0) ? 16384 : 8192;   // A half stride (bytes)
  constexpr int BOFF = (MODE == 0) ? 65536 : 32768;   // B base
  constexpr int BSLOT = (MODE == 0) ? 24576 : 16384;  // B slot stride
  constexpr int NVM = (MODE == 0) ? 3 : 2;            // counted vmcnt

  int wgid = (blockIdx.x & 7) * (gridDim.x >> 3) + (blockIdx.x >> 3);
  const int mt = wgid / nnt, nt = wgid % nnt;
  const int m0 = mt * ((MODE == 0) ? 256 : 128);
  const int n0 = nt * ((MODE == 0) ? 192 : 128);

  const int kswz = (((tid & 7) ^ ((tid >> 3) & 7)) << 4);
  const char* arow = (const char*)A + (size_t)(m0 + (tid >> 3)) * 8192 + kswz;
  const char* brow = (const char*)Bt + (size_t)(n0 + (tid >> 3)) * 8192 + kswz;

  auto stageA = [&](int t, int h) {
    if constexpr (MODE == 0) {
#pragma unroll
      for (int rd = 0; rd < 2; ++rd)
        gload_lds16(arow + (size_t)(h * 128 + rd * 64) * 8192 + t * 128,
                    smem + ((t & 1) * 2 + h) * AHALF + rd * 8192 + w * 1024);
    } else {
      gload_lds16(arow + (size_t)(h * 64) * 8192 + t * 128,
                  smem + ((t & 1) * 2 + h) * AHALF + w * 1024);
    }
  };
  auto stageB = [&](int t) {
    if constexpr (MODE == 0) {
#pragma unroll
      for (int rd = 0; rd < 3; ++rd)
        gload_lds16(brow + (size_t)(rd * 64) * 8192 + t * 128,
                    smem + BOFF + (t & 1) * BSLOT + rd * 8192 + w * 1024);
    } else {
#pragma unroll
      for (int rd = 0; rd < 2; ++rd)
        gload_lds16(brow + (size_t)(rd * 64) * 8192 + t * 128,
                    smem + BOFF + (t & 1) * BSLOT + rd * 8192 + w * 1024);
    }
  };

  constexpr int MF = (MODE == 0) ? 8 : 4;
  f32x4 acc[MF][NF];
#pragma unroll
  for (int i = 0; i < MF; ++i)
#pragma unroll
    for (int j = 0; j < NF; ++j) acc[i][j] = (f32x4){0.f, 0.f, 0.f, 0.f};

  const int aoff0 = ((l4) ^ (l15 & 7)) << 4;
  const int aoff1 = ((4 + l4) ^ (l15 & 7)) << 4;

  stageA(0, 0); stageA(0, 1);
  stageB(0); stageB(1);
  if constexpr (MODE == 0)
    asm volatile("s_waitcnt vmcnt(3)" ::: "memory");
  else
    asm volatile("s_waitcnt vmcnt(2)" ::: "memory");
  __builtin_amdgcn_s_barrier();

  auto do_iter = [&](int t0, int last) {
    bf16x8 bfr[NF][2];
#pragma unroll
    for (int p = 0; p < 8; ++p) {
      const int s = p >> 2, qd = p & 3;
      const char* aT = smem + (s * 2 + wr) * AHALF + l15 * 128;
      bf16x8 afr[(MODE == 0) ? 2 : 1][2];
      if constexpr (MODE == 0) {
#pragma unroll
        for (int jm = 0; jm < 2; ++jm) {
          afr[jm][0] = *(const bf16x8*)(aT + (2 * qd + jm) * 2048 + aoff0);
          afr[jm][1] = *(const bf16x8*)(aT + (2 * qd + jm) * 2048 + aoff1);
        }
      } else {
        afr[0][0] = *(const bf16x8*)(aT + qd * 2048 + aoff0);
        afr[0][1] = *(const bf16x8*)(aT + qd * 2048 + aoff1);
      }
      if (qd == 0) {
        const char* bT = smem + BOFF + s * BSLOT + (wc * BNW + l15) * 128;
#pragma unroll
        for (int nf = 0; nf < NF; ++nf) {
          bfr[nf][0] = *(const bf16x8*)(bT + nf * 2048 + aoff0);
          bfr[nf][1] = *(const bf16x8*)(bT + nf * 2048 + aoff1);
        }
      }
      if (p == 0) { stageA(t0 + 1, 0); stageA(t0 + 1, 1); }
      if (!last) {
        if (p == 1) stageB(t0 + 2);
        if (p == 4) { stageA(t0 + 2, 0); stageA(t0 + 2, 1); }
        if (p == 5) stageB(t0 + 3);
      }
      if (p == 3) {
        if (last) asm volatile("s_waitcnt vmcnt(0)" ::: "memory");
        else      asm volatile("s_waitcnt vmcnt(%0)" ::"i"(NVM): "memory");
      }
      if (p == 7 && !last)
        asm volatile("s_waitcnt vmcnt(%0)" ::"i"(NVM): "memory");
      __builtin_amdgcn_s_barrier();
      asm volatile("s_waitcnt lgkmcnt(0)" ::: "memory");
      __builtin_amdgcn_sched_barrier(0);
      __builtin_amdgcn_s_setprio(1);
      if constexpr (MODE == 0) {
#pragma unroll
        for (int ks = 0; ks < 2; ++ks)
#pragma unroll
          for (int jm = 0; jm < 2; ++jm)
#pragma unroll
            for (int nf = 0; nf < NF; ++nf)
              acc[2 * qd + jm][nf] =
                  mfma16(afr[jm][ks], bfr[nf][ks], acc[2 * qd + jm][nf]);
      } else {
#pragma unroll
        for (int ks = 0; ks < 2; ++ks)
#pragma unroll
          for (int nf = 0; nf < NF; ++nf)
            acc[qd][nf] = mfma16(afr[0][ks], bfr[nf][ks], acc[qd][nf]);
      }
      __builtin_amdgcn_s_setprio(0);
      __builtin_amdgcn_s_barrier();
    }
  };

  for (int j = 0; j < 31; ++j) do_iter(2 * j, 0);
  do_iter(62, 1);

  if (MODE == 0) {
    u16* qkp = (u16*)C0;
#pragma unroll
    for (int mf = 0; mf < MF; ++mf)
#pragma unroll
      for (int nf = 0; nf < NF; ++nf) {
        int ng = n0 + wc * BNW + nf * 16 + l15;
        if (ng < 5120) {
#pragma unroll
          for (int r = 0; r < 4; ++r) {
            int mg = m0 + wr * 128 + mf * 16 + l4 * 4 + r;
            qkp[(size_t)mg * 5120 + ng] = f2bf(acc[mf][nf][r]);
          }
        } else {
          int vr = ng - 5120;
          int mg = m0 + wr * 128 + mf * 16 + l4 * 4;
          ushort4 pk;
          pk.x = f2bf(acc[mf][nf][0]); pk.y = f2bf(acc[mf][nf][1]);
          pk.z = f2bf(acc[mf][nf][2]); pk.w = f2bf(acc[mf][nf][3]);
          *(ushort4*)&Vt[(size_t)vr * 2048 + mg] = pk;
        }
      }
  } else {
    float* Cp = (float*)C0;
#pragma unroll
    for (int mf = 0; mf < MF; ++mf)
#pragma unroll
      for (int nf = 0; nf < NF; ++nf) {
        int ng = n0 + wc * BNW + nf * 16 + l15;
#pragma unroll
        for (int r = 0; r < 4; ++r) {
          int mg = m0 + wr * 64 + mf * 16 + l4 * 4 + r;
          Cp[(size_t)mg * 4096 + ng] = acc[mf][nf][r];
        }
      }
  }
}

// ---------------- GQA flash attention (4 waves x 32q, 2 blocks/CU) ----------------
// qk: [2048][5120] bf16 (post-rope, Q pre-scaled); vt: [1024][2048] bf16;
// oat: [2048][4096] bf16. Block: 4 waves x 32 q = 128 q rows, 256 thr.
// Grid 512, dbuf K/V, K=32 PV with verified shfl P-redistribution.
__global__ __launch_bounds__(256, 2) void attn_kernel(const u16* __restrict__ qk,
                                                      const u16* __restrict__ vt,
                                                      u16* __restrict__ oat,
                                                      const float* __restrict__ mask,
                                                      const int* __restrict__ flag) {
  __shared__ u16 k_lds[2][64 * 128];  // [kv][d], 256B rows, chunk^(row&15)
  __shared__ u16 v_lds[2][64 * 128];  // [d=128][kv=64], 128B rows, chunk^(row&7)

  const int tid = threadIdx.x, lane = tid & 63, w = tid >> 6;
  const int l15 = lane & 15, l4 = lane >> 4;
  const int bid = blockIdx.x;
  const int hk = bid & 7;          // XCD-pinned kv head
  const int rest = bid >> 3;       // 0..63
  const int h = hk * 4 + (rest & 3);
  const int qt = rest >> 2;        // 0..15
  const int qbase = qt * 128 + w * 32;

  const bool use_mask = (*flag != 0);
  const char* kbase = (const char*)qk + 8192 + (size_t)hk * 256;
  const char* vbase = (const char*)vt + (size_t)hk * 128 * 4096;

  bf16x8 qf[2][4];
#pragma unroll
  for (int qg = 0; qg < 2; ++qg) {
    const char* qp = (const char*)qk +
                     (size_t)(qbase + qg * 16 + l15) * 10240 + h * 256 + l4 * 16;
#pragma unroll
    for (int ks = 0; ks < 4; ++ks) qf[qg][ks] = *(const bf16x8*)(qp + ks * 64);
  }

  f32x4 oacc[2][8];
#pragma unroll
  for (int qg = 0; qg < 2; ++qg)
#pragma unroll
    for (int fd = 0; fd < 8; ++fd) oacc[qg][fd] = (f32x4){0.f, 0.f, 0.f, 0.f};
  float m_run[2] = {-1e30f, -1e30f};
  float l_run[2] = {0.f, 0.f};

  int koff[4], voff[2];
#pragma unroll
  for (int ks = 0; ks < 4; ++ks) koff[ks] = ((4 * ks + l4) ^ l15) << 4;
#pragma unroll
  for (int ks = 0; ks < 2; ++ks) voff[ks] = ((4 * ks + l4) ^ (l15 & 7)) << 4;

#define STAGE(buf, kv0)                                                        \
  {                                                                            \
    _Pragma("unroll") for (int rd = 0; rd < 4; ++rd) {                         \
      int c = rd * 256 + tid;                                                  \
      int row = c >> 4;                                                        \
      int src = ((c & 15) ^ (row & 15)) << 4;                                  \
      gload_lds16(kbase + (size_t)((kv0) + row) * 10240 + src,                 \
                  (char*)k_lds[buf] + (rd * 256 + w * 64) * 16);               \
      int rowv = c >> 3;                                                       \
      int srcv = ((c & 7) ^ (rowv & 7)) << 4;                                  \
      gload_lds16(vbase + (size_t)rowv * 4096 + (kv0) * 2 + srcv,              \
                  (char*)v_lds[buf] + (rd * 256 + w * 64) * 16);               \
    }                                                                          \
  }

  STAGE(0, 0);
  asm volatile("s_waitcnt vmcnt(0)" ::: "memory");
  __builtin_amdgcn_s_barrier();
  __builtin_amdgcn_sched_barrier(0);

  for (int kt = 0; kt < 32; ++kt) {
    const int cur = kt & 1;
    const int kv0 = kt * 64;
    if (kt < 31) STAGE(cur ^ 1, kv0 + 64);

    f32x4 sA[2][4];
#pragma unroll
    for (int qg = 0; qg < 2; ++qg)
#pragma unroll
      for (int f = 0; f < 4; ++f) sA[qg][f] = (f32x4){0.f, 0.f, 0.f, 0.f};

    __builtin_amdgcn_s_setprio(1);
#pragma unroll
    for (int ks = 0; ks < 4; ++ks) {
      bf16x8 kfr[4];
#pragma unroll
      for (int f = 0; f < 4; ++f)
        kfr[f] = *(const bf16x8*)((const char*)k_lds[cur] +
                                  (16 * f + l15) * 256 + koff[ks]);
#pragma unroll
      for (int f = 0; f < 4; ++f) {
        sA[0][f] = mfma16(kfr[f], qf[0][ks], sA[0][f]);
        sA[1][f] = mfma16(kfr[f], qf[1][ks], sA[1][f]);
      }
    }
    __builtin_amdgcn_s_setprio(0);

    if (use_mask) {
#pragma unroll
      for (int qg = 0; qg < 2; ++qg) {
        int qglob = qbase + qg * 16 + l15;
#pragma unroll
        for (int f = 0; f < 4; ++f)
#pragma unroll
          for (int r = 0; r < 4; ++r) {
            int kvglob = kv0 + 16 * f + 4 * l4 + r;
            sA[qg][f][r] += LOG2E_F * mask[(size_t)qglob * 2048 + kvglob];
          }
      }
    }

    unsigned paw[2][2][4];
#pragma unroll
    for (int qg = 0; qg < 2; ++qg) {
      float mx = fmaxf(fmaxf(fmaxf(sA[qg][0][0], sA[qg][0][1]),
                             fmaxf(sA[qg][0][2], sA[qg][0][3])),
                       fmaxf(fmaxf(sA[qg][1][0], sA[qg][1][1]),
                             fmaxf(sA[qg][1][2], sA[qg][1][3])));
      float mx2 = fmaxf(fmaxf(fmaxf(sA[qg][2][0], sA[qg][2][1]),
                              fmaxf(sA[qg][2][2], sA[qg][2][3])),
                        fmaxf(fmaxf(sA[qg][3][0], sA[qg][3][1]),
                              fmaxf(sA[qg][3][2], sA[qg][3][3])));
      mx = fmaxf(mx, mx2);
      mx = fmaxf(mx, __shfl_xor(mx, 16));
      mx = fmaxf(mx, __shfl_xor(mx, 32));
      if (__any(mx > m_run[qg] + 8.0f)) {
        float mnew = fmaxf(m_run[qg], mx);
        float a = exp2a(m_run[qg] - mnew);
        l_run[qg] *= a;
        m_run[qg] = mnew;
        float a0 = __shfl(a, 4 * l4 + 0);
        float a1 = __shfl(a, 4 * l4 + 1);
        float a2 = __shfl(a, 4 * l4 + 2);
        float a3 = __shfl(a, 4 * l4 + 3);
#pragma unroll
        for (int fd = 0; fd < 8; ++fd) {
          oacc[qg][fd][0] *= a0; oacc[qg][fd][1] *= a1;
          oacc[qg][fd][2] *= a2; oacc[qg][fd][3] *= a3;
        }
      }
      float ps = 0.f;
      unsigned W[4][2];
#pragma unroll
      for (int f = 0; f < 4; ++f) {
        float p0 = exp2a(sA[qg][f][0] - m_run[qg]);
        float p1 = exp2a(sA[qg][f][1] - m_run[qg]);
        float p2 = exp2a(sA[qg][f][2] - m_run[qg]);
        float p3 = exp2a(sA[qg][f][3] - m_run[qg]);
        ps += (p0 + p1) + (p2 + p3);
        W[f][0] = cvtpk(p0, p1);
        W[f][1] = cvtpk(p2, p3);
      }
      ps += __shfl_xor(ps, 16);
      ps += __shfl_xor(ps, 32);
      l_run[qg] += ps;
#pragma unroll
      for (int ks = 0; ks < 2; ++ks)
#pragma unroll
        for (int wd = 0; wd < 4; ++wd) {
          int src = l15 + 16 * (2 * (l4 & 1) + (wd >> 1));
          unsigned v0 = (unsigned)__shfl((int)W[2 * ks][wd & 1], src);
          unsigned v1 = (unsigned)__shfl((int)W[2 * ks + 1][wd & 1], src);
          paw[qg][ks][wd] = (l4 & 2) ? v1 : v0;
        }
    }

    __builtin_amdgcn_s_setprio(1);
#pragma unroll
    for (int ks = 0; ks < 2; ++ks) {
      union { unsigned u[4]; bf16x8 v; } pa0, pa1;
#pragma unroll
      for (int wd = 0; wd < 4; ++wd) {
        pa0.u[wd] = paw[0][ks][wd];
        pa1.u[wd] = paw[1][ks][wd];
      }
#pragma unroll
      for (int fd = 0; fd < 8; ++fd) {
        bf16x8 vb = *(const bf16x8*)((const char*)v_lds[cur] +
                                     (16 * fd + l15) * 128 + voff[ks]);
        oacc[0][fd] = mfma16(pa0.v, vb, oacc[0][fd]);
        oacc[1][fd] = mfma16(pa1.v, vb, oacc[1][fd]);
      }
    }
    __builtin_amdgcn_s_setprio(0);

    if (kt < 31) {
      asm volatile("s_waitcnt vmcnt(0)" ::: "memory");
      __builtin_amdgcn_s_barrier();
      __builtin_amdgcn_sched_barrier(0);
    }
  }

#pragma unroll
  for (int qg = 0; qg < 2; ++qg) {
    float inv[4];
#pragma unroll
    for (int r = 0; r < 4; ++r) inv[r] = 1.0f / __shfl(l_run[qg], 4 * l4 + r);
#pragma unroll
    for (int fd = 0; fd < 8; ++fd) {
      int dg = h * 128 + 16 * fd + l15;
#pragma unroll
      for (int r = 0; r < 4; ++r) {
        int qrow = qbase + qg * 16 + 4 * l4 + r;
        oat[(size_t)qrow * 4096 + dg] = f2bf(oacc[qg][fd][r] * inv[r]);
      }
    }
  }
#undef STAGE
}

// ---------------- launch ----------------
extern "C" void kernel_launch(void* const* d_in, const int* in_sizes, int n_in,
                              void* d_out, int out_size, void* d_ws, size_t ws_size,
                              hipStream_t stream) {
  const float* x = (const float*)d_in[0];
  const int* row_ids = (const int*)d_in[1];
  const int* col_ids = (const int*)d_in[2];
  const float* mask = (const float*)d_in[3];
  const float* Wq = (const float*)d_in[4];
  const float* Wk = (const float*)d_in[5];
  const float* Wv = (const float*)d_in[6];
  const float* Wo = (const float*)d_in[7];
  const float* qw = (const float*)d_in[8];
  const float* kw = (const float*)d_in[9];

  char* ws = (char*)d_ws;
  u16* xb      = (u16*)(ws);                 // [0, 16MB)   dead after gemm<0>
  u16* wqkvt   = (u16*)(ws + 16777216);      // [16, 64MB)  dead after gemm<0>
  u16* wot     = (u16*)(ws + 67108864);      // [64, 96MB)
  u16* qkbuf   = (u16*)(ws + 100663296);
  u16* vtbuf   = (u16*)(ws + 121634816);
  u16* oat     = (u16*)(ws + 125829120);
  float4* trig = (float4*)(ws + 142606336);
  int* flag    = (int*)(ws + 143654912);

  hipFuncSetAttribute((const void*)gemm256<0>,
                      hipFuncAttributeMaxDynamicSharedMemorySize, 131072);
  hipFuncSetAttribute((const void*)gemm256<1>,
                      hipFuncAttributeMaxDynamicSharedMemorySize, 131072);

  hipMemsetAsync(flag, 0, 4, stream);
  setup<<<22784, 256, 0, stream>>>(Wq, Wk, Wv, Wo, wqkvt, wot,
                                   (const float4*)x, (ushort4*)xb,
                                   (const float4*)mask, flag, row_ids, col_ids,
                                   trig);
  gemm256<0><<<256, 512, 114688, stream>>>(xb, wqkvt, (void*)qkbuf, vtbuf, 32);
  rope_kernel<<<2048, 256, 0, stream>>>(qkbuf, trig, qw, kw);
  attn_kernel<<<512, 256, 0, stream>>>(qkbuf, vtbuf, oat, mask, flag);
  gemm256<1><<<512, 512, 65536, stream>>>(oat, wot, d_out, nullptr, 32);
}

// Round 14
// 348.798 us; speedup vs baseline: 1.0049x; 1.0049x over previous
//
#include <hip/hip_runtime.h>
#include <hip/hip_bf16.h>

typedef unsigned short u16;
typedef __attribute__((ext_vector_type(8))) short bf16x8;
typedef __attribute__((ext_vector_type(4))) float f32x4;

#define LOG2E_F 1.4426950408889634f
#define QSCALE (0.08838834764831845f * 7.625595228825695f * 1.4426950408889634f)

__device__ __forceinline__ u16 f2bf(float f) {
  unsigned x = __float_as_uint(f);
  unsigned r = (x + 0x7fffu + ((x >> 16) & 1u)) >> 16;  // RNE
  return (u16)r;
}
__device__ __forceinline__ float bf2f(u16 u) {
  return __uint_as_float(((unsigned)u) << 16);
}
__device__ __forceinline__ float exp2a(float x) {
  float r;
  asm("v_exp_f32 %0, %1" : "=v"(r) : "v"(x));
  return r;
}
__device__ __forceinline__ unsigned cvtpk(float lo, float hi) {
  unsigned r;
  asm("v_cvt_pk_bf16_f32 %0, %1, %2" : "=v"(r) : "v"(lo), "v"(hi));
  return r;
}

__device__ __forceinline__ void gload_lds16(const void* g, void* l) {
  __builtin_amdgcn_global_load_lds(
      (__attribute__((address_space(1))) void*)(g),
      (__attribute__((address_space(3))) void*)(l), 16, 0, 0);
}

__device__ __forceinline__ f32x4 mfma16(bf16x8 a, bf16x8 b, f32x4 c) {
  return __builtin_amdgcn_mfma_f32_16x16x32_bf16(a, b, c, 0, 0, 0);
}

// ---- fused setup: weight transpose+convert, x convert, maskflag, trig ----
__global__ __launch_bounds__(256) void setup(const float* __restrict__ Wq,
                                             const float* __restrict__ Wk,
                                             const float* __restrict__ Wv,
                                             const float* __restrict__ Wo,
                                             u16* __restrict__ wqkvt,
                                             u16* __restrict__ wot,
                                             const float4* __restrict__ x,
                                             ushort4* __restrict__ xb,
                                             const float4* __restrict__ mask,
                                             int* __restrict__ flag,
                                             const int* __restrict__ row_ids,
                                             const int* __restrict__ col_ids,
                                             float4* __restrict__ trig) {
  int bid = blockIdx.x;
  int tid = threadIdx.x;
  if (bid >= 10240) {
    bid -= 10240;
    if (bid < 8192) {  // cvt_x: 2048x4096 f32 -> bf16
      size_t i = (size_t)bid * 256 + tid;
      float4 v = x[i];
      ushort4 o;
      o.x = f2bf(v.x); o.y = f2bf(v.y); o.z = f2bf(v.z); o.w = f2bf(v.w);
      xb[i] = o;
    } else if (bid < 12288) {  // maskflag: 2048x2048
      size_t i = (size_t)(bid - 8192) * 256 + tid;
      float4 v = mask[i];
      if (v.x != 0.f || v.y != 0.f || v.z != 0.f || v.w != 0.f) atomicOr(flag, 1);
    } else {  // trig: 2048 tokens x 32 freqs
      int idx = (bid - 12288) * 256 + tid;
      int tok = idx >> 5, i = idx & 31;
      float inv = exp2f(-(float)i * 0.41524101186092030f);
      float ar = (float)row_ids[tok] * inv;
      float ac = (float)col_ids[tok] * inv * 1.618033988749895f;
      float4 o;
      o.x = cosf(ar); o.y = sinf(ar); o.z = cosf(ac); o.w = sinf(ac);
      trig[idx] = o;
    }
    return;
  }
  // weight transpose+convert: W [4096][N] f32 -> Wt [N][4096] bf16
  __shared__ float t[64][65];
  const float* src;
  u16* dst;
  int N;
  if (bid < 4096)      { src = Wq; dst = wqkvt;                       N = 4096; }
  else if (bid < 5120) { src = Wk; dst = wqkvt + (size_t)4096 * 4096; N = 1024; bid -= 4096; }
  else if (bid < 6144) { src = Wv; dst = wqkvt + (size_t)5120 * 4096; N = 1024; bid -= 5120; }
  else                 { src = Wo; dst = wot;                         N = 4096; bid -= 6144; }
  int kt = bid & 63, nt = bid >> 6;
  int k0 = kt * 64, n0 = nt * 64;
#pragma unroll
  for (int it = 0; it < 16; ++it) {
    int idx = it * 256 + tid;
    int row = idx >> 6, col = idx & 63;
    t[row][col] = src[(size_t)(k0 + row) * N + n0 + col];
  }
  __syncthreads();
#pragma unroll
  for (int it = 0; it < 8; ++it) {
    int idx = it * 256 + tid;
    int nrow = idx >> 5, kc = idx & 31;
    ushort2 o;
    o.x = f2bf(t[kc * 2][nrow]);
    o.y = f2bf(t[kc * 2 + 1][nrow]);
    *(ushort2*)&dst[(size_t)(n0 + nrow) * 4096 + k0 + kc * 2] = o;
  }
}

// ---------------- RMSNorm + gg-RoPE (in-place on QK buffer) ----------------
__global__ __launch_bounds__(256) void rope_kernel(u16* __restrict__ qk,
                                                   const float4* __restrict__ trig,
                                                   const float* __restrict__ qw,
                                                   const float* __restrict__ kw) {
  const int tok = blockIdx.x;
  const int tid = threadIdx.x;
  const int w = tid >> 6, lane = tid & 63;
  float4 t4 = trig[tok * 32 + (lane & 31)];
  float sgn = (lane < 32) ? -1.0f : 1.0f;

  for (int it = 0; it < 10; ++it) {
    int hh = w + it * 4;
    bool isQ = (hh < 32);
    int colbase = isQ ? hh * 128 : 4096 + (hh - 32) * 128;
    const float* nw = isQ ? qw : kw;
    float scale = isQ ? QSCALE : 1.0f;
    u16* p = qk + (size_t)tok * 5120 + colbase;
    float v1 = bf2f(p[lane]);
    float v2 = bf2f(p[64 + lane]);
    float w1 = nw[lane], w2 = nw[64 + lane];
    float ss = v1 * v1 + v2 * v2;
    ss += __shfl_xor(ss, 1);  ss += __shfl_xor(ss, 2);  ss += __shfl_xor(ss, 4);
    ss += __shfl_xor(ss, 8);  ss += __shfl_xor(ss, 16); ss += __shfl_xor(ss, 32);
    float rinv = rsqrtf(ss * (1.0f / 128.0f) + 1e-6f);
    float n1 = v1 * rinv * w1;
    float n2 = v2 * rinv * w2;
    float p1 = __shfl_xor(n1, 32);
    float p2 = __shfl_xor(n2, 32);
    float r1 = n1 * t4.x + sgn * p1 * t4.y;
    float r2 = n2 * t4.z + sgn * p2 * t4.w;
    p[lane]      = f2bf(r1 * scale);
    p[64 + lane] = f2bf(r2 * scale);
  }
}

// ======== 256-wide 8-phase GEMM: C[M][N] = A[M][4096] * Bt[N][4096]^T ========
// MODE 0: BM=256, BN=192 -> grid 8x32=256 (1/CU). Out: qk bf16 / Vt transposed.
// MODE 1: BM=256, BN=256, split-K=2 -> grid 2x128=256 (1/CU). Out: f32 partials.
template <int MODE>
__global__ __launch_bounds__(512, 2) void gemm256(const u16* __restrict__ A,
                                                  const u16* __restrict__ Bt,
                                                  void* __restrict__ C0,
                                                  u16* __restrict__ Vt, int nnt) {
  extern __shared__ char smem[];
  const int tid = threadIdx.x, lane = tid & 63, w = tid >> 6;
  const int l15 = lane & 15, l4 = lane >> 4;
  const int wr = w >> 2, wc = w & 3;
  constexpr int NF = (MODE == 0) ? 3 : 4;
  constexpr int BNW = (MODE == 0) ? 48 : 64;

  int wgid = (blockIdx.x & 7) * (gridDim.x >> 3) + (blockIdx.x >> 3);
  int kh = 0;
  if (MODE == 1) { kh = wgid >> 7; wgid &= 127; }
  const int mt = wgid / nnt, nt = wgid % nnt;
  const int m0 = mt * 256;
  const int n0 = nt * ((MODE == 0) ? 192 : 256);
  const int tbase = kh * 32;

  const int kswz = (((tid & 7) ^ ((tid >> 3) & 7)) << 4);
  const char* arow = (const char*)A + (size_t)(m0 + (tid >> 3)) * 8192 + kswz;
  const char* brow = (const char*)Bt + (size_t)(n0 + (tid >> 3)) * 8192 + kswz;

  auto stageA = [&](int t, int h) {
#pragma unroll
    for (int rd = 0; rd < 2; ++rd)
      gload_lds16(arow + (size_t)(h * 128 + rd * 64) * 8192 + t * 128,
                  smem + ((t & 1) * 2 + h) * 16384 + rd * 8192 + w * 1024);
  };
  auto stageB0 = [&](int t) {
#pragma unroll
    for (int rd = 0; rd < 3; ++rd)
      gload_lds16(brow + (size_t)(rd * 64) * 8192 + t * 128,
                  smem + 65536 + (t & 1) * 24576 + rd * 8192 + w * 1024);
  };
  auto stageB1 = [&](int t, int h) {
#pragma unroll
    for (int rd = 0; rd < 2; ++rd)
      gload_lds16(brow + (size_t)(h * 128 + rd * 64) * 8192 + t * 128,
                  smem + 65536 + ((t & 1) * 2 + h) * 16384 + rd * 8192 + w * 1024);
  };

  f32x4 acc[8][NF];
#pragma unroll
  for (int i = 0; i < 8; ++i)
#pragma unroll
    for (int j = 0; j < NF; ++j) acc[i][j] = (f32x4){0.f, 0.f, 0.f, 0.f};

  const int aoff0 = ((l4) ^ (l15 & 7)) << 4;
  const int aoff1 = ((4 + l4) ^ (l15 & 7)) << 4;

  stageA(tbase, 0); stageA(tbase, 1);
  if constexpr (MODE == 0) {
    stageB0(tbase); stageB0(tbase + 1);
    asm volatile("s_waitcnt vmcnt(3)" ::: "memory");
  } else {
    stageB1(tbase, 0); stageB1(tbase, 1);
    stageB1(tbase + 1, 0); stageB1(tbase + 1, 1);
    asm volatile("s_waitcnt vmcnt(4)" ::: "memory");
  }
  __builtin_amdgcn_s_barrier();

  auto do_iter = [&](int t0, int last) {
    bf16x8 bfr[NF][2];
#pragma unroll
    for (int p = 0; p < 8; ++p) {
      const int s = p >> 2, qd = p & 3;
      const char* aT = smem + (s * 2 + wr) * 16384 + l15 * 128;
      bf16x8 afr[2][2];
#pragma unroll
      for (int jm = 0; jm < 2; ++jm) {
        afr[jm][0] = *(const bf16x8*)(aT + (2 * qd + jm) * 2048 + aoff0);
        afr[jm][1] = *(const bf16x8*)(aT + (2 * qd + jm) * 2048 + aoff1);
      }
      if (qd == 0) {
        const char* bT;
        if constexpr (MODE == 0)
          bT = smem + 65536 + s * 24576 + (wc * 48 + l15) * 128;
        else
          bT = smem + 65536 + (s * 2 + (wc >> 1)) * 16384 +
               ((wc & 1) * 64 + l15) * 128;
#pragma unroll
        for (int nf = 0; nf < NF; ++nf) {
          bfr[nf][0] = *(const bf16x8*)(bT + nf * 2048 + aoff0);
          bfr[nf][1] = *(const bf16x8*)(bT + nf * 2048 + aoff1);
        }
      }
      if (p == 0) { stageA(t0 + 1, 0); stageA(t0 + 1, 1); }
      if (!last) {
        if constexpr (MODE == 0) {
          if (p == 1) stageB0(t0 + 2);
          if (p == 5) stageB0(t0 + 3);
        } else {
          if (p == 1) stageB1(t0 + 2, 0);
          if (p == 2) stageB1(t0 + 2, 1);
          if (p == 5) stageB1(t0 + 3, 0);
          if (p == 6) stageB1(t0 + 3, 1);
        }
        if (p == 4) { stageA(t0 + 2, 0); stageA(t0 + 2, 1); }
      }
      if (p == 3) {
        if (last) asm volatile("s_waitcnt vmcnt(0)" ::: "memory");
        else if constexpr (MODE == 0)
          asm volatile("s_waitcnt vmcnt(3)" ::: "memory");
        else
          asm volatile("s_waitcnt vmcnt(4)" ::: "memory");
      }
      if (p == 7 && !last) {
        if constexpr (MODE == 0)
          asm volatile("s_waitcnt vmcnt(3)" ::: "memory");
        else
          asm volatile("s_waitcnt vmcnt(4)" ::: "memory");
      }
      __builtin_amdgcn_s_barrier();
      asm volatile("s_waitcnt lgkmcnt(0)" ::: "memory");
      __builtin_amdgcn_sched_barrier(0);
      __builtin_amdgcn_s_setprio(1);
#pragma unroll
      for (int ks = 0; ks < 2; ++ks)
#pragma unroll
        for (int jm = 0; jm < 2; ++jm)
#pragma unroll
          for (int nf = 0; nf < NF; ++nf)
            acc[2 * qd + jm][nf] =
                mfma16(afr[jm][ks], bfr[nf][ks], acc[2 * qd + jm][nf]);
      __builtin_amdgcn_s_setprio(0);
      __builtin_amdgcn_s_barrier();
    }
  };

  constexpr int NIT = (MODE == 0) ? 32 : 16;
  for (int j = 0; j < NIT - 1; ++j) do_iter(tbase + 2 * j, 0);
  do_iter(tbase + 2 * (NIT - 1), 1);

  if (MODE == 0) {
    u16* qkp = (u16*)C0;
#pragma unroll
    for (int mf = 0; mf < 8; ++mf)
#pragma unroll
      for (int nf = 0; nf < NF; ++nf) {
        int ng = n0 + wc * BNW + nf * 16 + l15;
        if (ng < 5120) {
#pragma unroll
          for (int r = 0; r < 4; ++r) {
            int mg = m0 + wr * 128 + mf * 16 + l4 * 4 + r;
            qkp[(size_t)mg * 5120 + ng] = f2bf(acc[mf][nf][r]);
          }
        } else {
          int vr = ng - 5120;
          int mg = m0 + wr * 128 + mf * 16 + l4 * 4;
          ushort4 pk;
          pk.x = f2bf(acc[mf][nf][0]); pk.y = f2bf(acc[mf][nf][1]);
          pk.z = f2bf(acc[mf][nf][2]); pk.w = f2bf(acc[mf][nf][3]);
          *(ushort4*)&Vt[(size_t)vr * 2048 + mg] = pk;
        }
      }
  } else {
    float* Cp = (float*)C0 + (size_t)kh * 8388608;
#pragma unroll
    for (int mf = 0; mf < 8; ++mf)
#pragma unroll
      for (int nf = 0; nf < NF; ++nf) {
        int ng = n0 + wc * BNW + nf * 16 + l15;
#pragma unroll
        for (int r = 0; r < 4; ++r) {
          int mg = m0 + wr * 128 + mf * 16 + l4 * 4 + r;
          Cp[(size_t)mg * 4096 + ng] = acc[mf][nf][r];
        }
      }
  }
}

// ---------------- split-K reduce: out = p0 + p1 ----------------
__global__ __launch_bounds__(256) void reduce2(const float4* __restrict__ p0,
                                               const float4* __restrict__ p1,
                                               float4* __restrict__ out) {
  size_t i = (size_t)blockIdx.x * 256 + threadIdx.x;
  float4 a = p0[i], b = p1[i];
  float4 o;
  o.x = a.x + b.x; o.y = a.y + b.y; o.z = a.z + b.z; o.w = a.w + b.w;
  out[i] = o;
}

// ---------------- GQA flash attention (8 waves x 32q, in-register P) ----------------
// qk: [2048][5120] bf16 (post-rope, Q pre-scaled by QSCALE incl. log2e)
// vt: [1024][2048] bf16 (V transposed: row = hk*128+d, col = t)
// oat: [2048][4096] bf16
// block: 8 waves x 32 q = 256 q rows, 512 thr; kv step 64; grid 256 (8 qt x 32 h)
// hk = bid&7 -> XCD-pinned K/V. One block/CU stages K/V ONCE per CU (no duplication).
__global__ __launch_bounds__(512, 2) void attn_kernel(const u16* __restrict__ qk,
                                                      const u16* __restrict__ vt,
                                                      u16* __restrict__ oat,
                                                      const float* __restrict__ mask,
                                                      const int* __restrict__ flag) {
  __shared__ u16 k_lds[2][64 * 128];  // [kv][d], 256B rows, chunk^(row&15)
  __shared__ u16 v_lds[2][64 * 128];  // [d=128][kv=64], 128B rows, chunk^(row&7)

  const int tid = threadIdx.x, lane = tid & 63, w = tid >> 6;
  const int l15 = lane & 15, l4 = lane >> 4;
  const int bid = blockIdx.x;
  const int hk = bid & 7;          // XCD-pinned kv head
  const int rest = bid >> 3;       // 0..31
  const int h = hk * 4 + (rest & 3);
  const int qt = rest >> 2;        // 0..7
  const int qbase = qt * 256 + w * 32;

  const bool use_mask = (*flag != 0);
  const char* kbase = (const char*)qk + 8192 + (size_t)hk * 256;
  const char* vbase = (const char*)vt + (size_t)hk * 128 * 4096;

  // Q fragments: qf[qg][ks], B-operand (col=q=l15, k=d)
  bf16x8 qf[2][4];
#pragma unroll
  for (int qg = 0; qg < 2; ++qg) {
    const char* qp = (const char*)qk +
                     (size_t)(qbase + qg * 16 + l15) * 10240 + h * 256 + l4 * 16;
#pragma unroll
    for (int ks = 0; ks < 4; ++ks) qf[qg][ks] = *(const bf16x8*)(qp + ks * 64);
  }

  f32x4 oacc[2][8];
#pragma unroll
  for (int qg = 0; qg < 2; ++qg)
#pragma unroll
    for (int fd = 0; fd < 8; ++fd) oacc[qg][fd] = (f32x4){0.f, 0.f, 0.f, 0.f};
  float m_run[2] = {-1e30f, -1e30f};
  float l_run[2] = {0.f, 0.f};

  int koff[4], voff[2];
#pragma unroll
  for (int ks = 0; ks < 4; ++ks) koff[ks] = ((4 * ks + l4) ^ l15) << 4;
#pragma unroll
  for (int ks = 0; ks < 2; ++ks) voff[ks] = ((4 * ks + l4) ^ (l15 & 7)) << 4;

  // 512-thread staging: K 1024 chunks (16/row), V 1024 chunks (8/row)
#define STAGE(buf, kv0)                                                        \
  {                                                                            \
    _Pragma("unroll") for (int rd = 0; rd < 2; ++rd) {                         \
      int c = rd * 512 + tid;                                                  \
      int row = c >> 4;                                                        \
      int src = ((c & 15) ^ (row & 15)) << 4;                                  \
      gload_lds16(kbase + (size_t)((kv0) + row) * 10240 + src,                 \
                  (char*)k_lds[buf] + (rd * 512 + w * 64) * 16);               \
      int rowv = c >> 3;                                                       \
      int srcv = ((c & 7) ^ (rowv & 7)) << 4;                                  \
      gload_lds16(vbase + (size_t)rowv * 4096 + (kv0) * 2 + srcv,              \
                  (char*)v_lds[buf] + (rd * 512 + w * 64) * 16);               \
    }                                                                          \
  }

  STAGE(0, 0);
  asm volatile("s_waitcnt vmcnt(0)" ::: "memory");
  __builtin_amdgcn_s_barrier();
  __builtin_amdgcn_sched_barrier(0);

  for (int kt = 0; kt < 32; ++kt) {
    const int cur = kt & 1;
    const int kv0 = kt * 64;
    if (kt < 31) STAGE(cur ^ 1, kv0 + 64);

    // S^T = K-tile x Q  (rows = kv, cols = q = l15)
    f32x4 sA[2][4];
#pragma unroll
    for (int qg = 0; qg < 2; ++qg)
#pragma unroll
      for (int f = 0; f < 4; ++f) sA[qg][f] = (f32x4){0.f, 0.f, 0.f, 0.f};

    __builtin_amdgcn_s_setprio(1);
#pragma unroll
    for (int ks = 0; ks < 4; ++ks) {
      bf16x8 kfr[4];
#pragma unroll
      for (int f = 0; f < 4; ++f)
        kfr[f] = *(const bf16x8*)((const char*)k_lds[cur] +
                                  (16 * f + l15) * 256 + koff[ks]);
#pragma unroll
      for (int f = 0; f < 4; ++f) {
        sA[0][f] = mfma16(kfr[f], qf[0][ks], sA[0][f]);
        sA[1][f] = mfma16(kfr[f], qf[1][ks], sA[1][f]);
      }
    }
    __builtin_amdgcn_s_setprio(0);

    if (use_mask) {
#pragma unroll
      for (int qg = 0; qg < 2; ++qg) {
        int qglob = qbase + qg * 16 + l15;
#pragma unroll
        for (int f = 0; f < 4; ++f)
#pragma unroll
          for (int r = 0; r < 4; ++r) {
            int kvglob = kv0 + 16 * f + 4 * l4 + r;
            sA[qg][f][r] += LOG2E_F * mask[(size_t)qglob * 2048 + kvglob];
          }
      }
    }

    // online softmax; q lane-local (l15), kv in (f, l4, reg).
    // In-register P redistribution (verified R6): target word (ks,wd) at lane
    // (l15,l4) <- broadcast both f-blocks from src lane, select on (l4&2).
    unsigned paw[2][2][4];
#pragma unroll
    for (int qg = 0; qg < 2; ++qg) {
      float mx = fmaxf(fmaxf(fmaxf(sA[qg][0][0], sA[qg][0][1]),
                             fmaxf(sA[qg][0][2], sA[qg][0][3])),
                       fmaxf(fmaxf(sA[qg][1][0], sA[qg][1][1]),
                             fmaxf(sA[qg][1][2], sA[qg][1][3])));
      float mx2 = fmaxf(fmaxf(fmaxf(sA[qg][2][0], sA[qg][2][1]),
                              fmaxf(sA[qg][2][2], sA[qg][2][3])),
                        fmaxf(fmaxf(sA[qg][3][0], sA[qg][3][1]),
                              fmaxf(sA[qg][3][2], sA[qg][3][3])));
      mx = fmaxf(mx, mx2);
      mx = fmaxf(mx, __shfl_xor(mx, 16));
      mx = fmaxf(mx, __shfl_xor(mx, 32));
      if (__any(mx > m_run[qg] + 8.0f)) {
        float mnew = fmaxf(m_run[qg], mx);
        float a = exp2a(m_run[qg] - mnew);
        l_run[qg] *= a;
        m_run[qg] = mnew;
        float a0 = __shfl(a, 4 * l4 + 0);
        float a1 = __shfl(a, 4 * l4 + 1);
        float a2 = __shfl(a, 4 * l4 + 2);
        float a3 = __shfl(a, 4 * l4 + 3);
#pragma unroll
        for (int fd = 0; fd < 8; ++fd) {
          oacc[qg][fd][0] *= a0; oacc[qg][fd][1] *= a1;
          oacc[qg][fd][2] *= a2; oacc[qg][fd][3] *= a3;
        }
      }
      float ps = 0.f;
      unsigned W[4][2];
#pragma unroll
      for (int f = 0; f < 4; ++f) {
        float p0 = exp2a(sA[qg][f][0] - m_run[qg]);
        float p1 = exp2a(sA[qg][f][1] - m_run[qg]);
        float p2 = exp2a(sA[qg][f][2] - m_run[qg]);
        float p3 = exp2a(sA[qg][f][3] - m_run[qg]);
        ps += (p0 + p1) + (p2 + p3);
        W[f][0] = cvtpk(p0, p1);
        W[f][1] = cvtpk(p2, p3);
      }
      ps += __shfl_xor(ps, 16);
      ps += __shfl_xor(ps, 32);
      l_run[qg] += ps;
#pragma unroll
      for (int ks = 0; ks < 2; ++ks)
#pragma unroll
        for (int wd = 0; wd < 4; ++wd) {
          int src = l15 + 16 * (2 * (l4 & 1) + (wd >> 1));
          unsigned v0 = (unsigned)__shfl((int)W[2 * ks][wd & 1], src);
          unsigned v1 = (unsigned)__shfl((int)W[2 * ks + 1][wd & 1], src);
          paw[qg][ks][wd] = (l4 & 2) ? v1 : v0;
        }
    }

    // O += P V  (A = P in registers, B = Vt [d][kv] from LDS)
    __builtin_amdgcn_s_setprio(1);
#pragma unroll
    for (int ks = 0; ks < 2; ++ks) {
      union { unsigned u[4]; bf16x8 v; } pa0, pa1;
#pragma unroll
      for (int wd = 0; wd < 4; ++wd) {
        pa0.u[wd] = paw[0][ks][wd];
        pa1.u[wd] = paw[1][ks][wd];
      }
#pragma unroll
      for (int fd = 0; fd < 8; ++fd) {
        bf16x8 vb = *(const bf16x8*)((const char*)v_lds[cur] +
                                     (16 * fd + l15) * 128 + voff[ks]);
        oacc[0][fd] = mfma16(pa0.v, vb, oacc[0][fd]);
        oacc[1][fd] = mfma16(pa1.v, vb, oacc[1][fd]);
      }
    }
    __builtin_amdgcn_s_setprio(0);

    if (kt < 31) {
      asm volatile("s_waitcnt vmcnt(0)" ::: "memory");
      __builtin_amdgcn_s_barrier();
      __builtin_amdgcn_sched_barrier(0);
    }
  }

  // epilogue: broadcast l to C-layout lanes, normalize, write
#pragma unroll
  for (int qg = 0; qg < 2; ++qg) {
    float inv[4];
#pragma unroll
    for (int r = 0; r < 4; ++r) inv[r] = 1.0f / __shfl(l_run[qg], 4 * l4 + r);
#pragma unroll
    for (int fd = 0; fd < 8; ++fd) {
      int dg = h * 128 + 16 * fd + l15;
#pragma unroll
      for (int r = 0; r < 4; ++r) {
        int qrow = qbase + qg * 16 + 4 * l4 + r;
        oat[(size_t)qrow * 4096 + dg] = f2bf(oacc[qg][fd][r] * inv[r]);
      }
    }
  }
#undef STAGE
}

// ---------------- launch ----------------
extern "C" void kernel_launch(void* const* d_in, const int* in_sizes, int n_in,
                              void* d_out, int out_size, void* d_ws, size_t ws_size,
                              hipStream_t stream) {
  const float* x = (const float*)d_in[0];
  const int* row_ids = (const int*)d_in[1];
  const int* col_ids = (const int*)d_in[2];
  const float* mask = (const float*)d_in[3];
  const float* Wq = (const float*)d_in[4];
  const float* Wk = (const float*)d_in[5];
  const float* Wv = (const float*)d_in[6];
  const float* Wo = (const float*)d_in[7];
  const float* qw = (const float*)d_in[8];
  const float* kw = (const float*)d_in[9];

  char* ws = (char*)d_ws;
  u16* xb      = (u16*)(ws);                 // [0, 16MB)   dead after gemm<0>
  u16* wqkvt   = (u16*)(ws + 16777216);      // [16, 64MB)  dead after gemm<0>
  u16* wot     = (u16*)(ws + 67108864);      // [64, 96MB)
  u16* qkbuf   = (u16*)(ws + 100663296);
  u16* vtbuf   = (u16*)(ws + 121634816);
  u16* oat     = (u16*)(ws + 125829120);
  float4* trig = (float4*)(ws + 142606336);
  int* flag    = (int*)(ws + 143654912);
  float* pbuf  = (float*)(ws);               // [0, 64MB) gemm1 split-K partials

  hipFuncSetAttribute((const void*)gemm256<0>,
                      hipFuncAttributeMaxDynamicSharedMemorySize, 131072);
  hipFuncSetAttribute((const void*)gemm256<1>,
                      hipFuncAttributeMaxDynamicSharedMemorySize, 131072);

  hipMemsetAsync(flag, 0, 4, stream);
  setup<<<22784, 256, 0, stream>>>(Wq, Wk, Wv, Wo, wqkvt, wot,
                                   (const float4*)x, (ushort4*)xb,
                                   (const float4*)mask, flag, row_ids, col_ids,
                                   trig);
  gemm256<0><<<256, 512, 114688, stream>>>(xb, wqkvt, (void*)qkbuf, vtbuf, 32);
  rope_kernel<<<2048, 256, 0, stream>>>(qkbuf, trig, qw, kw);
  attn_kernel<<<256, 512, 0, stream>>>(qkbuf, vtbuf, oat, mask, flag);
  gemm256<1><<<256, 512, 131072, stream>>>(oat, wot, (void*)pbuf, nullptr, 16);
  reduce2<<<8192, 256, 0, stream>>>((const float4*)pbuf,
                                    (const float4*)(pbuf + 8388608),
                                    (float4*)d_out);
}

// Round 15
// 334.710 us; speedup vs baseline: 1.0472x; 1.0421x over previous
//
#include <hip/hip_runtime.h>
#include <hip/hip_bf16.h>

typedef unsigned short u16;
typedef __attribute__((ext_vector_type(8))) short bf16x8;
typedef __attribute__((ext_vector_type(4))) float f32x4;

#define LOG2E_F 1.4426950408889634f
#define QSCALE (0.08838834764831845f * 7.625595228825695f * 1.4426950408889634f)

__device__ __forceinline__ u16 f2bf(float f) {
  unsigned x = __float_as_uint(f);
  unsigned r = (x + 0x7fffu + ((x >> 16) & 1u)) >> 16;  // RNE
  return (u16)r;
}
__device__ __forceinline__ float bf2f(u16 u) {
  return __uint_as_float(((unsigned)u) << 16);
}
__device__ __forceinline__ float exp2a(float x) {
  float r;
  asm("v_exp_f32 %0, %1" : "=v"(r) : "v"(x));
  return r;
}
__device__ __forceinline__ unsigned cvtpk(float lo, float hi) {
  unsigned r;
  asm("v_cvt_pk_bf16_f32 %0, %1, %2" : "=v"(r) : "v"(lo), "v"(hi));
  return r;
}

__device__ __forceinline__ void gload_lds16(const void* g, void* l) {
  __builtin_amdgcn_global_load_lds(
      (__attribute__((address_space(1))) void*)(g),
      (__attribute__((address_space(3))) void*)(l), 16, 0, 0);
}

__device__ __forceinline__ f32x4 mfma16(bf16x8 a, bf16x8 b, f32x4 c) {
  return __builtin_amdgcn_mfma_f32_16x16x32_bf16(a, b, c, 0, 0, 0);
}

// ---- fused setup: weight transpose+convert, x convert, maskflag, trig ----
__global__ __launch_bounds__(256) void setup(const float* __restrict__ Wq,
                                             const float* __restrict__ Wk,
                                             const float* __restrict__ Wv,
                                             const float* __restrict__ Wo,
                                             u16* __restrict__ wqkvt,
                                             u16* __restrict__ wot,
                                             const float4* __restrict__ x,
                                             ushort4* __restrict__ xb,
                                             const float4* __restrict__ mask,
                                             int* __restrict__ flag,
                                             const int* __restrict__ row_ids,
                                             const int* __restrict__ col_ids,
                                             float4* __restrict__ trig) {
  int bid = blockIdx.x;
  int tid = threadIdx.x;
  if (bid >= 10240) {
    bid -= 10240;
    if (bid < 8192) {  // cvt_x: 2048x4096 f32 -> bf16
      size_t i = (size_t)bid * 256 + tid;
      float4 v = x[i];
      ushort4 o;
      o.x = f2bf(v.x); o.y = f2bf(v.y); o.z = f2bf(v.z); o.w = f2bf(v.w);
      xb[i] = o;
    } else if (bid < 12288) {  // maskflag: 2048x2048
      size_t i = (size_t)(bid - 8192) * 256 + tid;
      float4 v = mask[i];
      if (v.x != 0.f || v.y != 0.f || v.z != 0.f || v.w != 0.f) atomicOr(flag, 1);
    } else {  // trig: 2048 tokens x 32 freqs
      int idx = (bid - 12288) * 256 + tid;
      int tok = idx >> 5, i = idx & 31;
      float inv = exp2f(-(float)i * 0.41524101186092030f);
      float ar = (float)row_ids[tok] * inv;
      float ac = (float)col_ids[tok] * inv * 1.618033988749895f;
      float4 o;
      o.x = cosf(ar); o.y = sinf(ar); o.z = cosf(ac); o.w = sinf(ac);
      trig[idx] = o;
    }
    return;
  }
  // weight transpose+convert: W [4096][N] f32 -> Wt [N][4096] bf16
  __shared__ float t[64][65];
  const float* src;
  u16* dst;
  int N;
  if (bid < 4096)      { src = Wq; dst = wqkvt;                       N = 4096; }
  else if (bid < 5120) { src = Wk; dst = wqkvt + (size_t)4096 * 4096; N = 1024; bid -= 4096; }
  else if (bid < 6144) { src = Wv; dst = wqkvt + (size_t)5120 * 4096; N = 1024; bid -= 5120; }
  else                 { src = Wo; dst = wot;                         N = 4096; bid -= 6144; }
  int kt = bid & 63, nt = bid >> 6;
  int k0 = kt * 64, n0 = nt * 64;
#pragma unroll
  for (int it = 0; it < 16; ++it) {
    int idx = it * 256 + tid;
    int row = idx >> 6, col = idx & 63;
    t[row][col] = src[(size_t)(k0 + row) * N + n0 + col];
  }
  __syncthreads();
#pragma unroll
  for (int it = 0; it < 8; ++it) {
    int idx = it * 256 + tid;
    int nrow = idx >> 5, kc = idx & 31;
    ushort2 o;
    o.x = f2bf(t[kc * 2][nrow]);
    o.y = f2bf(t[kc * 2 + 1][nrow]);
    *(ushort2*)&dst[(size_t)(n0 + nrow) * 4096 + k0 + kc * 2] = o;
  }
}

// ---------------- RMSNorm + gg-RoPE (in-place on QK buffer) ----------------
__global__ __launch_bounds__(256) void rope_kernel(u16* __restrict__ qk,
                                                   const float4* __restrict__ trig,
                                                   const float* __restrict__ qw,
                                                   const float* __restrict__ kw) {
  const int tok = blockIdx.x;
  const int tid = threadIdx.x;
  const int w = tid >> 6, lane = tid & 63;
  float4 t4 = trig[tok * 32 + (lane & 31)];
  float sgn = (lane < 32) ? -1.0f : 1.0f;

  for (int it = 0; it < 10; ++it) {
    int hh = w + it * 4;
    bool isQ = (hh < 32);
    int colbase = isQ ? hh * 128 : 4096 + (hh - 32) * 128;
    const float* nw = isQ ? qw : kw;
    float scale = isQ ? QSCALE : 1.0f;
    u16* p = qk + (size_t)tok * 5120 + colbase;
    float v1 = bf2f(p[lane]);
    float v2 = bf2f(p[64 + lane]);
    float w1 = nw[lane], w2 = nw[64 + lane];
    float ss = v1 * v1 + v2 * v2;
    ss += __shfl_xor(ss, 1);  ss += __shfl_xor(ss, 2);  ss += __shfl_xor(ss, 4);
    ss += __shfl_xor(ss, 8);  ss += __shfl_xor(ss, 16); ss += __shfl_xor(ss, 32);
    float rinv = rsqrtf(ss * (1.0f / 128.0f) + 1e-6f);
    float n1 = v1 * rinv * w1;
    float n2 = v2 * rinv * w2;
    float p1 = __shfl_xor(n1, 32);
    float p2 = __shfl_xor(n2, 32);
    float r1 = n1 * t4.x + sgn * p1 * t4.y;
    float r2 = n2 * t4.z + sgn * p2 * t4.w;
    p[lane]      = f2bf(r1 * scale);
    p[64 + lane] = f2bf(r2 * scale);
  }
}

// ======== 256-wide 8-phase GEMM: C[M][N] = A[M][4096] * Bt[N][4096]^T ========
// MODE 0: BM=256, BN=192 -> grid 8x32=256 (1/CU). Out: qk bf16 / Vt transposed.
// MODE 1: BM=256, BN=256, split-K=2 -> grid 2x128=256 (1/CU). Out: f32 partials.
template <int MODE>
__global__ __launch_bounds__(512, 2) void gemm256(const u16* __restrict__ A,
                                                  const u16* __restrict__ Bt,
                                                  void* __restrict__ C0,
                                                  u16* __restrict__ Vt, int nnt) {
  extern __shared__ char smem[];
  const int tid = threadIdx.x, lane = tid & 63, w = tid >> 6;
  const int l15 = lane & 15, l4 = lane >> 4;
  const int wr = w >> 2, wc = w & 3;
  constexpr int NF = (MODE == 0) ? 3 : 4;
  constexpr int BNW = (MODE == 0) ? 48 : 64;

  int wgid = (blockIdx.x & 7) * (gridDim.x >> 3) + (blockIdx.x >> 3);
  int kh = 0;
  if (MODE == 1) { kh = wgid >> 7; wgid &= 127; }
  const int mt = wgid / nnt, nt = wgid % nnt;
  const int m0 = mt * 256;
  const int n0 = nt * ((MODE == 0) ? 192 : 256);
  const int tbase = kh * 32;

  const int kswz = (((tid & 7) ^ ((tid >> 3) & 7)) << 4);
  const char* arow = (const char*)A + (size_t)(m0 + (tid >> 3)) * 8192 + kswz;
  const char* brow = (const char*)Bt + (size_t)(n0 + (tid >> 3)) * 8192 + kswz;

  auto stageA = [&](int t, int h) {
#pragma unroll
    for (int rd = 0; rd < 2; ++rd)
      gload_lds16(arow + (size_t)(h * 128 + rd * 64) * 8192 + t * 128,
                  smem + ((t & 1) * 2 + h) * 16384 + rd * 8192 + w * 1024);
  };
  auto stageB0 = [&](int t) {
#pragma unroll
    for (int rd = 0; rd < 3; ++rd)
      gload_lds16(brow + (size_t)(rd * 64) * 8192 + t * 128,
                  smem + 65536 + (t & 1) * 24576 + rd * 8192 + w * 1024);
  };
  auto stageB1 = [&](int t, int h) {
#pragma unroll
    for (int rd = 0; rd < 2; ++rd)
      gload_lds16(brow + (size_t)(h * 128 + rd * 64) * 8192 + t * 128,
                  smem + 65536 + ((t & 1) * 2 + h) * 16384 + rd * 8192 + w * 1024);
  };

  f32x4 acc[8][NF];
#pragma unroll
  for (int i = 0; i < 8; ++i)
#pragma unroll
    for (int j = 0; j < NF; ++j) acc[i][j] = (f32x4){0.f, 0.f, 0.f, 0.f};

  const int aoff0 = ((l4) ^ (l15 & 7)) << 4;
  const int aoff1 = ((4 + l4) ^ (l15 & 7)) << 4;

  stageA(tbase, 0); stageA(tbase, 1);
  if constexpr (MODE == 0) {
    stageB0(tbase); stageB0(tbase + 1);
    asm volatile("s_waitcnt vmcnt(3)" ::: "memory");
  } else {
    stageB1(tbase, 0); stageB1(tbase, 1);
    stageB1(tbase + 1, 0); stageB1(tbase + 1, 1);
    asm volatile("s_waitcnt vmcnt(4)" ::: "memory");
  }
  __builtin_amdgcn_s_barrier();

  auto do_iter = [&](int t0, int last) {
    bf16x8 bfr[NF][2];
#pragma unroll
    for (int p = 0; p < 8; ++p) {
      const int s = p >> 2, qd = p & 3;
      const char* aT = smem + (s * 2 + wr) * 16384 + l15 * 128;
      bf16x8 afr[2][2];
#pragma unroll
      for (int jm = 0; jm < 2; ++jm) {
        afr[jm][0] = *(const bf16x8*)(aT + (2 * qd + jm) * 2048 + aoff0);
        afr[jm][1] = *(const bf16x8*)(aT + (2 * qd + jm) * 2048 + aoff1);
      }
      if (qd == 0) {
        const char* bT;
        if constexpr (MODE == 0)
          bT = smem + 65536 + s * 24576 + (wc * 48 + l15) * 128;
        else
          bT = smem + 65536 + (s * 2 + (wc >> 1)) * 16384 +
               ((wc & 1) * 64 + l15) * 128;
#pragma unroll
        for (int nf = 0; nf < NF; ++nf) {
          bfr[nf][0] = *(const bf16x8*)(bT + nf * 2048 + aoff0);
          bfr[nf][1] = *(const bf16x8*)(bT + nf * 2048 + aoff1);
        }
      }
      if (p == 0) { stageA(t0 + 1, 0); stageA(t0 + 1, 1); }
      if (!last) {
        if constexpr (MODE == 0) {
          if (p == 1) stageB0(t0 + 2);
          if (p == 5) stageB0(t0 + 3);
        } else {
          if (p == 1) stageB1(t0 + 2, 0);
          if (p == 2) stageB1(t0 + 2, 1);
          if (p == 5) stageB1(t0 + 3, 0);
          if (p == 6) stageB1(t0 + 3, 1);
        }
        if (p == 4) { stageA(t0 + 2, 0); stageA(t0 + 2, 1); }
      }
      if (p == 3) {
        if (last) asm volatile("s_waitcnt vmcnt(0)" ::: "memory");
        else if constexpr (MODE == 0)
          asm volatile("s_waitcnt vmcnt(3)" ::: "memory");
        else
          asm volatile("s_waitcnt vmcnt(4)" ::: "memory");
      }
      if (p == 7 && !last) {
        if constexpr (MODE == 0)
          asm volatile("s_waitcnt vmcnt(3)" ::: "memory");
        else
          asm volatile("s_waitcnt vmcnt(4)" ::: "memory");
      }
      __builtin_amdgcn_s_barrier();
      asm volatile("s_waitcnt lgkmcnt(0)" ::: "memory");
      __builtin_amdgcn_sched_barrier(0);
      __builtin_amdgcn_s_setprio(1);
#pragma unroll
      for (int ks = 0; ks < 2; ++ks)
#pragma unroll
        for (int jm = 0; jm < 2; ++jm)
#pragma unroll
          for (int nf = 0; nf < NF; ++nf)
            acc[2 * qd + jm][nf] =
                mfma16(afr[jm][ks], bfr[nf][ks], acc[2 * qd + jm][nf]);
      __builtin_amdgcn_s_setprio(0);
      __builtin_amdgcn_s_barrier();
    }
  };

  constexpr int NIT = (MODE == 0) ? 32 : 16;
  for (int j = 0; j < NIT - 1; ++j) do_iter(tbase + 2 * j, 0);
  do_iter(tbase + 2 * (NIT - 1), 1);

  if (MODE == 0) {
    u16* qkp = (u16*)C0;
#pragma unroll
    for (int mf = 0; mf < 8; ++mf)
#pragma unroll
      for (int nf = 0; nf < NF; ++nf) {
        int ng = n0 + wc * BNW + nf * 16 + l15;
        if (ng < 5120) {
#pragma unroll
          for (int r = 0; r < 4; ++r) {
            int mg = m0 + wr * 128 + mf * 16 + l4 * 4 + r;
            qkp[(size_t)mg * 5120 + ng] = f2bf(acc[mf][nf][r]);
          }
        } else {
          int vr = ng - 5120;
          int mg = m0 + wr * 128 + mf * 16 + l4 * 4;
          ushort4 pk;
          pk.x = f2bf(acc[mf][nf][0]); pk.y = f2bf(acc[mf][nf][1]);
          pk.z = f2bf(acc[mf][nf][2]); pk.w = f2bf(acc[mf][nf][3]);
          *(ushort4*)&Vt[(size_t)vr * 2048 + mg] = pk;
        }
      }
  } else {
    float* Cp = (float*)C0 + (size_t)kh * 8388608;
#pragma unroll
    for (int mf = 0; mf < 8; ++mf)
#pragma unroll
      for (int nf = 0; nf < NF; ++nf) {
        int ng = n0 + wc * BNW + nf * 16 + l15;
#pragma unroll
        for (int r = 0; r < 4; ++r) {
          int mg = m0 + wr * 128 + mf * 16 + l4 * 4 + r;
          Cp[(size_t)mg * 4096 + ng] = acc[mf][nf][r];
        }
      }
  }
}

// ---------------- split-K reduce: out = p0 + p1 ----------------
__global__ __launch_bounds__(256) void reduce2(const float4* __restrict__ p0,
                                               const float4* __restrict__ p1,
                                               float4* __restrict__ out) {
  size_t i = (size_t)blockIdx.x * 256 + threadIdx.x;
  float4 a = p0[i], b = p1[i];
  float4 o;
  o.x = a.x + b.x; o.y = a.y + b.y; o.z = a.z + b.z; o.w = a.w + b.w;
  out[i] = o;
}

// ---- GQA flash attention: 8 waves x 32q, KVBLK=128 (16 iters), dyn-LDS 128KB ----
// qk: [2048][5120] bf16 (post-rope, Q pre-scaled); vt: [1024][2048] bf16;
// oat: [2048][4096] bf16. Grid 256 (8 qt x 32 h), 512 thr, 1 block/CU.
// K_lds/V_lds: [2][128 rows][256B], chunk ^ (row&15) swizzle (both).
__global__ __launch_bounds__(512, 2) void attn_kernel(const u16* __restrict__ qk,
                                                      const u16* __restrict__ vt,
                                                      u16* __restrict__ oat,
                                                      const float* __restrict__ mask,
                                                      const int* __restrict__ flag) {
  extern __shared__ char asmem[];  // [0,64K): K dbuf ; [64K,128K): V dbuf
  char* kls = asmem;
  char* vls = asmem + 65536;

  const int tid = threadIdx.x, lane = tid & 63, w = tid >> 6;
  const int l15 = lane & 15, l4 = lane >> 4;
  const int bid = blockIdx.x;
  const int hk = bid & 7;          // XCD-pinned kv head
  const int rest = bid >> 3;       // 0..31
  const int h = hk * 4 + (rest & 3);
  const int qt = rest >> 2;        // 0..7
  const int qbase = qt * 256 + w * 32;

  const bool use_mask = (*flag != 0);
  const char* kbase = (const char*)qk + 8192 + (size_t)hk * 256;
  const char* vbase = (const char*)vt + (size_t)hk * 128 * 4096;

  // Q fragments: qf[qg][ks], B-operand (col=q=l15, k=d)
  bf16x8 qf[2][4];
#pragma unroll
  for (int qg = 0; qg < 2; ++qg) {
    const char* qp = (const char*)qk +
                     (size_t)(qbase + qg * 16 + l15) * 10240 + h * 256 + l4 * 16;
#pragma unroll
    for (int ks = 0; ks < 4; ++ks) qf[qg][ks] = *(const bf16x8*)(qp + ks * 64);
  }

  f32x4 oacc[2][8];
#pragma unroll
  for (int qg = 0; qg < 2; ++qg)
#pragma unroll
    for (int fd = 0; fd < 8; ++fd) oacc[qg][fd] = (f32x4){0.f, 0.f, 0.f, 0.f};
  float m_run[2] = {-1e30f, -1e30f};
  float l_run[2] = {0.f, 0.f};

  // shared read offsets (K rows and V rows both 256B, row&15 = l15)
  int koff[4];
#pragma unroll
  for (int ks = 0; ks < 4; ++ks) koff[ks] = ((4 * ks + l4) ^ l15) << 4;

  // stage one 128-kv tile: K 2048 chunks + V 2048 chunks, 512 threads
#define STAGE(buf, kv0)                                                        \
  {                                                                            \
    _Pragma("unroll") for (int rd = 0; rd < 4; ++rd) {                         \
      int c = rd * 512 + tid;                                                  \
      int row = c >> 4;                                                        \
      int sw = ((c & 15) ^ (row & 15)) << 4;                                   \
      gload_lds16(kbase + (size_t)((kv0) + row) * 10240 + sw,                  \
                  kls + (buf) * 32768 + (rd * 512 + w * 64) * 16);             \
      gload_lds16(vbase + (size_t)row * 4096 + (kv0) * 2 + sw,                 \
                  vls + (buf) * 32768 + (rd * 512 + w * 64) * 16);             \
    }                                                                          \
  }

  STAGE(0, 0);
  asm volatile("s_waitcnt vmcnt(0)" ::: "memory");
  __builtin_amdgcn_s_barrier();
  __builtin_amdgcn_sched_barrier(0);

  for (int kt = 0; kt < 16; ++kt) {
    const int cur = kt & 1;
    const int kv0 = kt * 128;
    if (kt < 15) STAGE(cur ^ 1, kv0 + 128);

    // S^T = K-tile x Q  (rows = kv 0..127, cols = q = l15)
    f32x4 sA[2][8];
#pragma unroll
    for (int qg = 0; qg < 2; ++qg)
#pragma unroll
      for (int f = 0; f < 8; ++f) sA[qg][f] = (f32x4){0.f, 0.f, 0.f, 0.f};

    __builtin_amdgcn_s_setprio(1);
#pragma unroll
    for (int ks = 0; ks < 4; ++ks) {
      bf16x8 kfr[8];
#pragma unroll
      for (int f = 0; f < 8; ++f)
        kfr[f] = *(const bf16x8*)(kls + cur * 32768 +
                                  (16 * f + l15) * 256 + koff[ks]);
#pragma unroll
      for (int f = 0; f < 8; ++f) {
        sA[0][f] = mfma16(kfr[f], qf[0][ks], sA[0][f]);
        sA[1][f] = mfma16(kfr[f], qf[1][ks], sA[1][f]);
      }
    }
    __builtin_amdgcn_s_setprio(0);

    if (use_mask) {
#pragma unroll
      for (int qg = 0; qg < 2; ++qg) {
        int qglob = qbase + qg * 16 + l15;
#pragma unroll
        for (int f = 0; f < 8; ++f)
#pragma unroll
          for (int r = 0; r < 4; ++r) {
            int kvglob = kv0 + 16 * f + 4 * l4 + r;
            sA[qg][f][r] += LOG2E_F * mask[(size_t)qglob * 2048 + kvglob];
          }
      }
    }

    // online softmax; q lane-local (l15), kv = 16f + 4*l4 + r (f 0..7).
    // In-register P redistribution: target word (ks,wd) at lane (l15,l4)
    //   <- src lane l15 + 16*(2*(l4&1)+(wd>>1)), value W[2ks+(l4>>1)][wd&1]
    //   (broadcast both f-blocks, select on l4&2). ks 0..3.
    unsigned paw[2][4][4];
#pragma unroll
    for (int qg = 0; qg < 2; ++qg) {
      float mx = sA[qg][0][0];
#pragma unroll
      for (int f = 0; f < 8; ++f)
#pragma unroll
        for (int r = 0; r < 4; ++r) mx = fmaxf(mx, sA[qg][f][r]);
      mx = fmaxf(mx, __shfl_xor(mx, 16));
      mx = fmaxf(mx, __shfl_xor(mx, 32));
      if (__any(mx > m_run[qg] + 8.0f)) {
        float mnew = fmaxf(m_run[qg], mx);
        float a = exp2a(m_run[qg] - mnew);
        l_run[qg] *= a;
        m_run[qg] = mnew;
        float a0 = __shfl(a, 4 * l4 + 0);
        float a1 = __shfl(a, 4 * l4 + 1);
        float a2 = __shfl(a, 4 * l4 + 2);
        float a3 = __shfl(a, 4 * l4 + 3);
#pragma unroll
        for (int fd = 0; fd < 8; ++fd) {
          oacc[qg][fd][0] *= a0; oacc[qg][fd][1] *= a1;
          oacc[qg][fd][2] *= a2; oacc[qg][fd][3] *= a3;
        }
      }
      float ps = 0.f;
      unsigned W[8][2];
#pragma unroll
      for (int f = 0; f < 8; ++f) {
        float p0 = exp2a(sA[qg][f][0] - m_run[qg]);
        float p1 = exp2a(sA[qg][f][1] - m_run[qg]);
        float p2 = exp2a(sA[qg][f][2] - m_run[qg]);
        float p3 = exp2a(sA[qg][f][3] - m_run[qg]);
        ps += (p0 + p1) + (p2 + p3);
        W[f][0] = cvtpk(p0, p1);
        W[f][1] = cvtpk(p2, p3);
      }
      ps += __shfl_xor(ps, 16);
      ps += __shfl_xor(ps, 32);
      l_run[qg] += ps;
#pragma unroll
      for (int ks = 0; ks < 4; ++ks)
#pragma unroll
        for (int wd = 0; wd < 4; ++wd) {
          int src = l15 + 16 * (2 * (l4 & 1) + (wd >> 1));
          unsigned v0 = (unsigned)__shfl((int)W[2 * ks][wd & 1], src);
          unsigned v1 = (unsigned)__shfl((int)W[2 * ks + 1][wd & 1], src);
          paw[qg][ks][wd] = (l4 & 2) ? v1 : v0;
        }
    }

    // O += P V  (A = P in registers, B = V [d][kv] from LDS, 256B rows)
    __builtin_amdgcn_s_setprio(1);
#pragma unroll
    for (int ks = 0; ks < 4; ++ks) {
      union { unsigned u[4]; bf16x8 v; } pa0, pa1;
#pragma unroll
      for (int wd = 0; wd < 4; ++wd) {
        pa0.u[wd] = paw[0][ks][wd];
        pa1.u[wd] = paw[1][ks][wd];
      }
#pragma unroll
      for (int fd = 0; fd < 8; ++fd) {
        bf16x8 vb = *(const bf16x8*)(vls + cur * 32768 +
                                     (16 * fd + l15) * 256 + koff[ks]);
        oacc[0][fd] = mfma16(pa0.v, vb, oacc[0][fd]);
        oacc[1][fd] = mfma16(pa1.v, vb, oacc[1][fd]);
      }
    }
    __builtin_amdgcn_s_setprio(0);

    if (kt < 15) {
      asm volatile("s_waitcnt vmcnt(0)" ::: "memory");
      __builtin_amdgcn_s_barrier();
      __builtin_amdgcn_sched_barrier(0);
    }
  }

  // epilogue: broadcast l to C-layout lanes, normalize, write
#pragma unroll
  for (int qg = 0; qg < 2; ++qg) {
    float inv[4];
#pragma unroll
    for (int r = 0; r < 4; ++r) inv[r] = 1.0f / __shfl(l_run[qg], 4 * l4 + r);
#pragma unroll
    for (int fd = 0; fd < 8; ++fd) {
      int dg = h * 128 + 16 * fd + l15;
#pragma unroll
      for (int r = 0; r < 4; ++r) {
        int qrow = qbase + qg * 16 + 4 * l4 + r;
        oat[(size_t)qrow * 4096 + dg] = f2bf(oacc[qg][fd][r] * inv[r]);
      }
    }
  }
#undef STAGE
}

// ---------------- launch ----------------
extern "C" void kernel_launch(void* const* d_in, const int* in_sizes, int n_in,
                              void* d_out, int out_size, void* d_ws, size_t ws_size,
                              hipStream_t stream) {
  const float* x = (const float*)d_in[0];
  const int* row_ids = (const int*)d_in[1];
  const int* col_ids = (const int*)d_in[2];
  const float* mask = (const float*)d_in[3];
  const float* Wq = (const float*)d_in[4];
  const float* Wk = (const float*)d_in[5];
  const float* Wv = (const float*)d_in[6];
  const float* Wo = (const float*)d_in[7];
  const float* qw = (const float*)d_in[8];
  const float* kw = (const float*)d_in[9];

  char* ws = (char*)d_ws;
  u16* xb      = (u16*)(ws);                 // [0, 16MB)   dead after gemm<0>
  u16* wqkvt   = (u16*)(ws + 16777216);      // [16, 64MB)  dead after gemm<0>
  u16* wot     = (u16*)(ws + 67108864);      // [64, 96MB)
  u16* qkbuf   = (u16*)(ws + 100663296);
  u16* vtbuf   = (u16*)(ws + 121634816);
  u16* oat     = (u16*)(ws + 125829120);
  float4* trig = (float4*)(ws + 142606336);
  int* flag    = (int*)(ws + 143654912);
  float* pbuf  = (float*)(ws);               // [0, 64MB) gemm1 split-K partials

  hipFuncSetAttribute((const void*)gemm256<0>,
                      hipFuncAttributeMaxDynamicSharedMemorySize, 131072);
  hipFuncSetAttribute((const void*)gemm256<1>,
                      hipFuncAttributeMaxDynamicSharedMemorySize, 131072);
  hipFuncSetAttribute((const void*)attn_kernel,
                      hipFuncAttributeMaxDynamicSharedMemorySize, 131072);

  hipMemsetAsync(flag, 0, 4, stream);
  setup<<<22784, 256, 0, stream>>>(Wq, Wk, Wv, Wo, wqkvt, wot,
                                   (const float4*)x, (ushort4*)xb,
                                   (const float4*)mask, flag, row_ids, col_ids,
                                   trig);
  gemm256<0><<<256, 512, 114688, stream>>>(xb, wqkvt, (void*)qkbuf, vtbuf, 32);
  rope_kernel<<<2048, 256, 0, stream>>>(qkbuf, trig, qw, kw);
  attn_kernel<<<256, 512, 131072, stream>>>(qkbuf, vtbuf, oat, mask, flag);
  gemm256<1><<<256, 512, 131072, stream>>>(oat, wot, (void*)pbuf, nullptr, 16);
  reduce2<<<8192, 256, 0, stream>>>((const float4*)pbuf,
                                    (const float4*)(pbuf + 8388608),
                                    (float4*)d_out);
}